// Round 3
// baseline (4496.896 us; speedup 1.0000x reference)
//
#include <hip/hip_runtime.h>
#include <math.h>

#define BB 64
#define TT 256
#define DD 1024
#define NROWS (BB * TT)          // 16384
#define KWTA_KEEP 128
#define NN ((size_t)NROWS * DD)  // 16,777,216 elements per buffer

// All heavy math in f64 to match the harness's numpy-f64 reference at the
// KWTA flip level: min boundary gap across 16384 rows ~2.5e-7; f32 h error
// ~1e-6 guarantees flips (round-1 absmax 1.67 == flip signature). f64 h error
// vs np ~1e-13.
//
// Scratch lives in a static __device__ array: 512 MB exceeded the harness's
// d_ws (round-2 core dump = OOB write on d_ws). Static device BSS is
// allocated at module load; no hipMalloc, graph-capture safe. Layout:
//   g_ws[0*NN)  Xn   (f64)
//   g_ws[1*NN)  R    (f64)
//   g_ws[2*NN)  K -> y (in place)
//   g_ws[3*NN)  V -> H (in place)
__device__ double g_ws[4 * NN];

// ---------------------------------------------------------------------------
// Kernel 1: RMSNorm per row (f32 in -> f64 out into g_ws[0..NN))
// ---------------------------------------------------------------------------
__global__ __launch_bounds__(256) void rmsnorm_k(const float* __restrict__ x,
                                                 const float* __restrict__ nw) {
    double* __restrict__ xn = g_ws;
    const int row = blockIdx.x;
    const float* xr = x + (size_t)row * DD;
    float4 v = ((const float4*)xr)[threadIdx.x];
    const double vx = v.x, vy = v.y, vz = v.z, vw = v.w;
    double ss = vx * vx + vy * vy + vz * vz + vw * vw;
    #pragma unroll
    for (int off = 32; off > 0; off >>= 1) ss += __shfl_down(ss, off, 64);
    __shared__ double sred[4];
    const int wid = threadIdx.x >> 6;
    if ((threadIdx.x & 63) == 0) sred[wid] = ss;
    __syncthreads();
    const double tot = sred[0] + sred[1] + sred[2] + sred[3];
    const double s = sqrt(tot * (1.0 / (double)DD) + 1e-5);
    float4 w = ((const float4*)nw)[threadIdx.x];
    double* o = xn + (size_t)row * DD + threadIdx.x * 4;
    double2 o0, o1;
    o0.x = (double)w.x * (vx / s);
    o0.y = (double)w.y * (vy / s);
    o1.x = (double)w.z * (vz / s);
    o1.y = (double)w.w * (vw / s);
    *(double2*)(o + 0) = o0;
    *(double2*)(o + 2) = o1;
}

// ---------------------------------------------------------------------------
// f64 GEMM core: C[m,n] = op( sum_k A[m,k] * W[n,k] )   A f64, W f32 (cast)
// 64x64 tile, BK=32, 256 threads, 4x4 f64 register tile per thread.
// ---------------------------------------------------------------------------
#define MODE_SIG 0
#define MODE_PLAIN 1
#define MODE_ADD 2

__device__ __forceinline__ void gemm_core_f64(const double* __restrict__ A,
                                              const float* __restrict__ W,
                                              double* __restrict__ C,
                                              const double* __restrict__ Xadd,
                                              const int mode) {
    __shared__ double As[32][66];   // [k][m], row stride 528B
    __shared__ double Bs[32][66];   // [k][n]
    const int tid = threadIdx.x;
    const int tx = tid & 15;
    const int ty = tid >> 4;
    const int m0 = blockIdx.y * 64;
    const int n0 = blockIdx.x * 64;

    double acc[4][4];
    #pragma unroll
    for (int i = 0; i < 4; ++i)
        #pragma unroll
        for (int j = 0; j < 4; ++j) acc[i][j] = 0.0;

    for (int k0 = 0; k0 < DD; k0 += 32) {
        #pragma unroll
        for (int L = 0; L < 4; ++L) {           // A tile: 64x32 f64
            const int fidx = tid + L * 256;     // [0,1024)
            const int r = fidx >> 4;            // [0,64)
            const int c2 = (fidx & 15) * 2;     // [0,32) step 2
            const double2 a = *(const double2*)(A + (size_t)(m0 + r) * DD + k0 + c2);
            As[c2][r] = a.x; As[c2 + 1][r] = a.y;
        }
        #pragma unroll
        for (int L = 0; L < 2; ++L) {           // W tile: 64x32 f32 -> f64
            const int fidx = tid + L * 256;     // [0,512)
            const int r = fidx >> 3;            // [0,64)
            const int c4 = (fidx & 7) * 4;      // [0,32) step 4
            const float4 b = *(const float4*)(W + (size_t)(n0 + r) * DD + k0 + c4);
            Bs[c4 + 0][r] = (double)b.x; Bs[c4 + 1][r] = (double)b.y;
            Bs[c4 + 2][r] = (double)b.z; Bs[c4 + 3][r] = (double)b.w;
        }
        __syncthreads();
        #pragma unroll
        for (int kk = 0; kk < 32; ++kk) {
            const double2 a0 = *(const double2*)&As[kk][ty << 2];
            const double2 a1 = *(const double2*)&As[kk][(ty << 2) + 2];
            const double2 b0 = *(const double2*)&Bs[kk][tx << 2];
            const double2 b1 = *(const double2*)&Bs[kk][(tx << 2) + 2];
            const double aa[4] = {a0.x, a0.y, a1.x, a1.y};
            const double bb[4] = {b0.x, b0.y, b1.x, b1.y};
            #pragma unroll
            for (int i = 0; i < 4; ++i)
                #pragma unroll
                for (int j = 0; j < 4; ++j)
                    acc[i][j] = fma(aa[i], bb[j], acc[i][j]);
        }
        __syncthreads();
    }

    #pragma unroll
    for (int i = 0; i < 4; ++i) {
        const int row = m0 + (ty << 2) + i;
        const int col0 = n0 + (tx << 2);
        double vv[4] = {acc[i][0], acc[i][1], acc[i][2], acc[i][3]};
        if (mode == MODE_SIG) {
            #pragma unroll
            for (int j = 0; j < 4; ++j) vv[j] = 1.0 / (1.0 + exp(-vv[j]));
        }
        if (mode == MODE_ADD) {
            const double2 xa0 = *(const double2*)(Xadd + (size_t)row * DD + col0);
            const double2 xa1 = *(const double2*)(Xadd + (size_t)row * DD + col0 + 2);
            vv[0] += xa0.x; vv[1] += xa0.y; vv[2] += xa1.x; vv[3] += xa1.y;
        }
        double2 o0, o1;
        o0.x = vv[0]; o0.y = vv[1]; o1.x = vv[2]; o1.y = vv[3];
        *(double2*)(C + (size_t)row * DD + col0) = o0;
        *(double2*)(C + (size_t)row * DD + col0 + 2) = o1;
    }
}

// R = sigmoid(Xn Wr^T), K = Xn Wk^T, V = Xn Wv^T   (z selects which)
__global__ __launch_bounds__(256) void gemm_rkv(const float* __restrict__ Wr,
                                                const float* __restrict__ Wk,
                                                const float* __restrict__ Wv) {
    const int z = blockIdx.z;
    const float* W = (z == 0) ? Wr : ((z == 1) ? Wk : Wv);
    double* C = g_ws + (size_t)(z + 1) * NN;
    gemm_core_f64(g_ws, W, C, nullptr, z == 0 ? MODE_SIG : MODE_PLAIN);
}

// H = Xn + Y Wo^T   (Y = g_ws[2*NN), H overwrites V at g_ws[3*NN))
__global__ __launch_bounds__(256) void gemm_wo(const float* __restrict__ Wo) {
    gemm_core_f64(g_ws + 2 * NN, Wo, g_ws + 3 * NN, g_ws, MODE_ADD);
}

// ---------------------------------------------------------------------------
// Kernel 3: per-channel recurrence over T (all f64). One thread per (b, d).
// Writes y in place of k.
// ---------------------------------------------------------------------------
__global__ __launch_bounds__(256) void recur_k(const float* __restrict__ sp,
                                               const float* __restrict__ decay) {
    double* __restrict__ Kb = g_ws + 2 * NN;
    const double* __restrict__ V = g_ws + 3 * NN;
    const double* __restrict__ R = g_ws + NN;

    const int g = blockIdx.x * 256 + threadIdx.x;
    const int b = g >> 10;
    const int d = g & (DD - 1);

    const double dp = (double)decay[d];
    const double sg = 1.0 / (1.0 + exp(-dp));
    const double lam = sg * sg;

    const bool rope = (d < 32);
    double wt = 0.0;
    if (rope) {
        const int m = d >> 1;
        // np.linspace(log(1/1e4), 0, 16): start + m*step, endpoint exact
        const double start = log(1.0 / 10000.0);
        const double step = (0.0 - start) / 15.0;
        const double val = (m == 15) ? 0.0 : (start + (double)m * step);
        wt = exp(val);
    }

    double num = 0.0, den = 0.0;
    const size_t base = (size_t)b * TT * DD + d;
    for (int t = 0; t < TT; ++t) {
        const size_t idx = base + (size_t)t * DD;
        const double k = Kb[idx];
        const double r = R[idx];
        double v = V[idx];
        if (rope) {
            const double vp = V[idx ^ 1ull];
            const double th = (double)sp[t] * wt;
            const double c_ = cos(th), s_ = sin(th);
            v = ((d & 1) == 0) ? (v * c_ - vp * s_) : (vp * s_ + v * c_);
        }
        const double w = exp(k);
        num = num * lam + w * v;
        den = den * lam + w;
        Kb[idx] = r * (num / (den + 1e-9));
    }
}

// ---------------------------------------------------------------------------
// Kernel 5: exact KWTA per row on f64 h; writes f32 out.
// thr = exact bit pattern of 128th-largest |h| via 63-step binary search on
// the nonnegative f64 bit pattern (order-isomorphic to the value).
// ---------------------------------------------------------------------------
__global__ __launch_bounds__(256) void kwta_k(float* __restrict__ out) {
    const double* __restrict__ H = g_ws + 3 * NN;
    const size_t base = (size_t)blockIdx.x * DD;
    const int tid = threadIdx.x;
    double h[4];
    unsigned long long u[4];
    #pragma unroll
    for (int j = 0; j < 4; ++j) {
        h[j] = H[base + tid + 256 * j];
        u[j] = __double_as_longlong(fabs(h[j]));
    }

    __shared__ int scnt[64];
    if (tid < 64) scnt[tid] = 0;
    __syncthreads();

    unsigned long long thr = 0ull;
    #pragma unroll 1
    for (int bit = 62; bit >= 0; --bit) {
        const unsigned long long cand = thr | (1ull << bit);
        int c = (u[0] >= cand) + (u[1] >= cand) + (u[2] >= cand) + (u[3] >= cand);
        #pragma unroll
        for (int off = 32; off > 0; off >>= 1) c += __shfl_down(c, off, 64);
        if ((tid & 63) == 0) atomicAdd(&scnt[bit], c);
        __syncthreads();
        if (scnt[bit] >= KWTA_KEEP) thr = cand;
    }

    #pragma unroll
    for (int j = 0; j < 4; ++j)
        out[base + tid + 256 * j] = (u[j] >= thr) ? (float)h[j] : 0.0f;
}

// ---------------------------------------------------------------------------
extern "C" void kernel_launch(void* const* d_in, const int* in_sizes, int n_in,
                              void* d_out, int out_size, void* d_ws, size_t ws_size,
                              hipStream_t stream) {
    const float* x    = (const float*)d_in[0];
    const float* sp   = (const float*)d_in[1];
    const float* nw   = (const float*)d_in[2];
    const float* Wr   = (const float*)d_in[3];
    const float* Wk   = (const float*)d_in[4];
    const float* Wv   = (const float*)d_in[5];
    const float* Wo   = (const float*)d_in[6];
    const float* dec  = (const float*)d_in[7];
    float* out = (float*)d_out;
    (void)d_ws; (void)ws_size;

    rmsnorm_k<<<NROWS, 256, 0, stream>>>(x, nw);

    dim3 g1(DD / 64, NROWS / 64, 3);
    gemm_rkv<<<g1, 256, 0, stream>>>(Wr, Wk, Wv);

    recur_k<<<(BB * DD) / 256, 256, 0, stream>>>(sp, dec);

    dim3 g2(DD / 64, NROWS / 64, 1);
    gemm_wo<<<g2, 256, 0, stream>>>(Wo);

    kwta_k<<<NROWS, 256, 0, stream>>>(out);
}

// Round 5
// 3923.215 us; speedup vs baseline: 1.1462x; 1.1462x over previous
//
#include <hip/hip_runtime.h>
#include <math.h>

#define BB 64
#define TT 256
#define DD 1024
#define NROWS (BB * TT)          // 16384
#define KWTA_KEEP 128
#define NN ((size_t)NROWS * DD)  // 16,777,216 elements per buffer

// f64 end-to-end (KWTA flip analysis, round 1/3: min boundary gap ~2.5e-7;
// f32 h error ~1e-6 flips; f64 passes at absmax 0.0156 = f64->f32 rounding).
// Scratch in static device BSS (512 MB > d_ws; round-2 abort was d_ws OOB).
//   g_ws[0*NN)  Xn   (f64)
//   g_ws[1*NN)  R    (f64)
//   g_ws[2*NN)  K -> y (in place)
//   g_ws[3*NN)  V -> H (in place)
__device__ double g_ws[4 * NN];

// ---------------------------------------------------------------------------
// Kernel 1: RMSNorm per row (f32 in -> f64 out)
// ---------------------------------------------------------------------------
__global__ __launch_bounds__(256) void rmsnorm_k(const float* __restrict__ x,
                                                 const float* __restrict__ nw) {
    double* __restrict__ xn = g_ws;
    const int row = blockIdx.x;
    const float* xr = x + (size_t)row * DD;
    float4 v = ((const float4*)xr)[threadIdx.x];
    const double vx = v.x, vy = v.y, vz = v.z, vw = v.w;
    double ss = vx * vx + vy * vy + vz * vz + vw * vw;
    #pragma unroll
    for (int off = 32; off > 0; off >>= 1) ss += __shfl_down(ss, off, 64);
    __shared__ double sred[4];
    const int wid = threadIdx.x >> 6;
    if ((threadIdx.x & 63) == 0) sred[wid] = ss;
    __syncthreads();
    const double tot = sred[0] + sred[1] + sred[2] + sred[3];
    const double s = sqrt(tot * (1.0 / (double)DD) + 1e-5);
    float4 w = ((const float4*)nw)[threadIdx.x];
    double* o = xn + (size_t)row * DD + threadIdx.x * 4;
    double2 o0, o1;
    o0.x = (double)w.x * (vx / s);
    o0.y = (double)w.y * (vy / s);
    o1.x = (double)w.z * (vz / s);
    o1.y = (double)w.w * (vw / s);
    *(double2*)(o + 0) = o0;
    *(double2*)(o + 2) = o1;
}

// ---------------------------------------------------------------------------
// Vector-f64 GEMM v2: C[m,n] = op( sum_k A[m,k] * W[n,k] )  A f64, W f32.
// 128x128 tile, BK=16, 256 threads, 8x8 STRIDED register tile per thread
// (row = ty + 16*i, col = tx + 16*j).
// LDS: k-contiguous (no transpose staging). A as f64 stride-17 doubles
// (reads: bank = (2*ty + 2*kk)%32, broadcast over tx -> conflict-free).
// B kept f32 stride-17 floats (odd stride: bank = (17*tx+16*j+kk)%32, 17*tx
// bijective mod 32 -> 16 distinct banks -> conflict-free), cvt on read.
// Each C element is a sequential k=0..1023 fma chain -> bit-identical to the
// round-3 passing kernel.
// ---------------------------------------------------------------------------
#define MODE_SIG 0
#define MODE_PLAIN 1
#define MODE_ADD 2

#define BM 128
#define BN 128
#define BKK 16
#define LDA 17   // doubles per As row
#define LDB 17   // floats per Bs row

__device__ __forceinline__ void gemm_vec_f64(const double* __restrict__ A,
                                             const float* __restrict__ W,
                                             double* __restrict__ C,
                                             const double* __restrict__ Xadd,
                                             const int mode) {
    __shared__ double As[BM * LDA];   // 17408 B
    __shared__ float  Bs[BN * LDB];   //  8704 B
    const int tid = threadIdx.x;
    const int tx = tid & 15;
    const int ty = tid >> 4;
    const int m0 = blockIdx.y * BM;
    const int n0 = blockIdx.x * BN;

    double acc[8][8];
    #pragma unroll
    for (int i = 0; i < 8; ++i)
        #pragma unroll
        for (int j = 0; j < 8; ++j) acc[i][j] = 0.0;

    double2 pa[4];
    float4 pb[2];

    // A: c -> row c>>3, double2-granule c&7 (8 thr cover a row's 128 B).
    // B: c -> row c>>2, float4-granule c&3 (4 thr cover a row's 64 B).
    #define LOADG(k0)                                                          \
        {                                                                      \
            _Pragma("unroll")                                                  \
            for (int i = 0; i < 4; ++i) {                                      \
                const int c = tid + 256 * i;                                   \
                pa[i] = *(const double2*)(A + (size_t)(m0 + (c >> 3)) * DD +   \
                                          (k0) + (c & 7) * 2);                 \
            }                                                                  \
            _Pragma("unroll")                                                  \
            for (int i = 0; i < 2; ++i) {                                      \
                const int c = tid + 256 * i;                                   \
                pb[i] = *(const float4*)(W + (size_t)(n0 + (c >> 2)) * DD +    \
                                         (k0) + (c & 3) * 4);                  \
            }                                                                  \
        }

    LOADG(0);

    for (int k0 = 0; k0 < DD; k0 += BKK) {
        __syncthreads();   // previous compute done; LDS reusable
        #pragma unroll
        for (int i = 0; i < 4; ++i) {
            const int c = tid + 256 * i;
            const int base = (c >> 3) * LDA + (c & 7) * 2;
            As[base] = pa[i].x;
            As[base + 1] = pa[i].y;
        }
        #pragma unroll
        for (int i = 0; i < 2; ++i) {
            const int c = tid + 256 * i;
            const int base = (c >> 2) * LDB + (c & 3) * 4;
            Bs[base + 0] = pb[i].x;
            Bs[base + 1] = pb[i].y;
            Bs[base + 2] = pb[i].z;
            Bs[base + 3] = pb[i].w;
        }
        __syncthreads();
        if (k0 + BKK < DD) LOADG(k0 + BKK);

        #pragma unroll
        for (int kk = 0; kk < BKK; ++kk) {
            double a[8], b[8];
            #pragma unroll
            for (int i = 0; i < 8; ++i) a[i] = As[(ty + 16 * i) * LDA + kk];
            #pragma unroll
            for (int j = 0; j < 8; ++j) b[j] = (double)Bs[(tx + 16 * j) * LDB + kk];
            #pragma unroll
            for (int i = 0; i < 8; ++i)
                #pragma unroll
                for (int j = 0; j < 8; ++j)
                    acc[i][j] = fma(a[i], b[j], acc[i][j]);
        }
    }
    #undef LOADG

    #pragma unroll
    for (int i = 0; i < 8; ++i) {
        const int row = m0 + ty + 16 * i;
        #pragma unroll
        for (int j = 0; j < 8; ++j) {
            const int col = n0 + tx + 16 * j;
            double v = acc[i][j];
            if (mode == MODE_SIG) v = 1.0 / (1.0 + exp(-v));
            if (mode == MODE_ADD) v += Xadd[(size_t)row * DD + col];
            C[(size_t)row * DD + col] = v;
        }
    }
}

// R = sigmoid(Xn Wr^T), K = Xn Wk^T, V = Xn Wv^T   (z selects which)
__global__ __launch_bounds__(256, 2) void gemm_rkv(const float* __restrict__ Wr,
                                                   const float* __restrict__ Wk,
                                                   const float* __restrict__ Wv) {
    const int z = blockIdx.z;
    const float* W = (z == 0) ? Wr : ((z == 1) ? Wk : Wv);
    double* C = g_ws + (size_t)(z + 1) * NN;
    gemm_vec_f64(g_ws, W, C, nullptr, z == 0 ? MODE_SIG : MODE_PLAIN);
}

// H = Xn + Y Wo^T   (Y = g_ws[2*NN), H overwrites V at g_ws[3*NN))
__global__ __launch_bounds__(256, 2) void gemm_wo(const float* __restrict__ Wo) {
    gemm_vec_f64(g_ws + 2 * NN, Wo, g_ws + 3 * NN, g_ws, MODE_ADD);
}

// ---------------------------------------------------------------------------
// Kernel 3: per-channel recurrence over T (all f64). One thread per (b, d).
// ---------------------------------------------------------------------------
__global__ __launch_bounds__(256) void recur_k(const float* __restrict__ sp,
                                               const float* __restrict__ decay) {
    double* __restrict__ Kb = g_ws + 2 * NN;
    const double* __restrict__ V = g_ws + 3 * NN;
    const double* __restrict__ R = g_ws + NN;

    const int g = blockIdx.x * 256 + threadIdx.x;
    const int b = g >> 10;
    const int d = g & (DD - 1);

    const double dp = (double)decay[d];
    const double sg = 1.0 / (1.0 + exp(-dp));
    const double lam = sg * sg;

    const bool rope = (d < 32);
    double wt = 0.0;
    if (rope) {
        const int m = d >> 1;
        const double start = log(1.0 / 10000.0);
        const double step = (0.0 - start) / 15.0;
        const double val = (m == 15) ? 0.0 : (start + (double)m * step);
        wt = exp(val);
    }

    double num = 0.0, den = 0.0;
    const size_t base = (size_t)b * TT * DD + d;
    for (int t = 0; t < TT; ++t) {
        const size_t idx = base + (size_t)t * DD;
        const double k = Kb[idx];
        const double r = R[idx];
        double v = V[idx];
        if (rope) {
            const double vp = V[idx ^ 1ull];
            const double th = (double)sp[t] * wt;
            const double c_ = cos(th), s_ = sin(th);
            v = ((d & 1) == 0) ? (v * c_ - vp * s_) : (vp * s_ + v * c_);
        }
        const double w = exp(k);
        num = num * lam + w * v;
        den = den * lam + w;
        Kb[idx] = r * (num / (den + 1e-9));
    }
}

// ---------------------------------------------------------------------------
// Kernel 5: exact KWTA per row on f64 h; writes f32 out.
// ---------------------------------------------------------------------------
__global__ __launch_bounds__(256) void kwta_k(float* __restrict__ out) {
    const double* __restrict__ H = g_ws + 3 * NN;
    const size_t base = (size_t)blockIdx.x * DD;
    const int tid = threadIdx.x;
    double h[4];
    unsigned long long u[4];
    #pragma unroll
    for (int j = 0; j < 4; ++j) {
        h[j] = H[base + tid + 256 * j];
        u[j] = __double_as_longlong(fabs(h[j]));
    }

    __shared__ int scnt[64];
    if (tid < 64) scnt[tid] = 0;
    __syncthreads();

    unsigned long long thr = 0ull;
    #pragma unroll 1
    for (int bit = 62; bit >= 0; --bit) {
        const unsigned long long cand = thr | (1ull << bit);
        int c = (u[0] >= cand) + (u[1] >= cand) + (u[2] >= cand) + (u[3] >= cand);
        #pragma unroll
        for (int off = 32; off > 0; off >>= 1) c += __shfl_down(c, off, 64);
        if ((tid & 63) == 0) atomicAdd(&scnt[bit], c);
        __syncthreads();
        if (scnt[bit] >= KWTA_KEEP) thr = cand;
    }

    #pragma unroll
    for (int j = 0; j < 4; ++j)
        out[base + tid + 256 * j] = (u[j] >= thr) ? (float)h[j] : 0.0f;
}

// ---------------------------------------------------------------------------
extern "C" void kernel_launch(void* const* d_in, const int* in_sizes, int n_in,
                              void* d_out, int out_size, void* d_ws, size_t ws_size,
                              hipStream_t stream) {
    const float* x    = (const float*)d_in[0];
    const float* sp   = (const float*)d_in[1];
    const float* nw   = (const float*)d_in[2];
    const float* Wr   = (const float*)d_in[3];
    const float* Wk   = (const float*)d_in[4];
    const float* Wv   = (const float*)d_in[5];
    const float* Wo   = (const float*)d_in[6];
    const float* dec  = (const float*)d_in[7];
    float* out = (float*)d_out;
    (void)d_ws; (void)ws_size;

    rmsnorm_k<<<NROWS, 256, 0, stream>>>(x, nw);

    dim3 g1(DD / BN, NROWS / BM, 3);
    gemm_rkv<<<g1, 256, 0, stream>>>(Wr, Wk, Wv);

    recur_k<<<(BB * DD) / 256, 256, 0, stream>>>(sp, dec);

    dim3 g2(DD / BN, NROWS / BM, 1);
    gemm_wo<<<g2, 256, 0, stream>>>(Wo);

    kwta_k<<<NROWS, 256, 0, stream>>>(out);
}

// Round 9
// 2840.438 us; speedup vs baseline: 1.5832x; 1.3812x over previous
//
#include <hip/hip_runtime.h>
#include <math.h>

#define BB 64
#define TT 256
#define DD 1024
#define NROWS (BB * TT)          // 16384
#define KWTA_KEEP 128
#define NN ((size_t)NROWS * DD)  // 16,777,216 elements per buffer

// f64 end-to-end (KWTA flip analysis, rounds 1/3: min boundary gap ~2.5e-7
// over 16384 rows; f32 h error ~1e-6 flips; f64 passes at absmax 0.0156).
// Scratch in static device BSS (512 MB > d_ws; round-2 abort was d_ws OOB).
//   g_ws[0*NN)  Xn   (f64)
//   g_ws[1*NN)  R    (f64)
//   g_ws[2*NN)  K -> y (in place)
//   g_ws[3*NN)  V -> H (in place)
__device__ double g_ws[4 * NN];

typedef __attribute__((ext_vector_type(4))) double dx4;

// ---------------------------------------------------------------------------
// Kernel 0: MFMA f64 C/D-layout probe (1 wave). AMD docs show two reg->row
// variants across instr families (4*(l>>4)+r vs (l>>4)+4*r); round-4's
// absmax-2.92 failure has exactly the fixed-point structure of that swap.
// Probe: mfma(a=lane, b=0.25) -> D[m][n] = m + 24 (A[m][k]=m+16k summed*0.25)
//        mfma(a=0.25, b=lane) -> D[m][n] = n + 24
// Each (lane,reg) decodes its true (row,col); epilogue writes through table.
// ---------------------------------------------------------------------------
__global__ __launch_bounds__(64) void probe_k(int* __restrict__ maps) {
    const int l = threadIdx.x;
    dx4 z = {0.0, 0.0, 0.0, 0.0};
    dx4 dr = __builtin_amdgcn_mfma_f64_16x16x4f64((double)l, 0.25, z, 0, 0, 0);
    dx4 dc = __builtin_amdgcn_mfma_f64_16x16x4f64(0.25, (double)l, z, 0, 0, 0);
    #pragma unroll
    for (int r = 0; r < 4; ++r) {
        maps[l * 4 + r] = (int)(dr[r] + 0.5) - 24;
        maps[256 + l * 4 + r] = (int)(dc[r] + 0.5) - 24;
    }
}

// ---------------------------------------------------------------------------
// Kernel 1: RMSNorm per row (f32 in -> f64 out)
// ---------------------------------------------------------------------------
__global__ __launch_bounds__(256) void rmsnorm_k(const float* __restrict__ x,
                                                 const float* __restrict__ nw) {
    double* __restrict__ xn = g_ws;
    const int row = blockIdx.x;
    const float* xr = x + (size_t)row * DD;
    float4 v = ((const float4*)xr)[threadIdx.x];
    const double vx = v.x, vy = v.y, vz = v.z, vw = v.w;
    double ss = vx * vx + vy * vy + vz * vz + vw * vw;
    #pragma unroll
    for (int off = 32; off > 0; off >>= 1) ss += __shfl_down(ss, off, 64);
    __shared__ double sred[4];
    const int wid = threadIdx.x >> 6;
    if ((threadIdx.x & 63) == 0) sred[wid] = ss;
    __syncthreads();
    const double tot = sred[0] + sred[1] + sred[2] + sred[3];
    const double s = sqrt(tot * (1.0 / (double)DD) + 1e-5);
    float4 w = ((const float4*)nw)[threadIdx.x];
    double* o = xn + (size_t)row * DD + threadIdx.x * 4;
    double2 o0, o1;
    o0.x = (double)w.x * (vx / s);
    o0.y = (double)w.y * (vy / s);
    o1.x = (double)w.z * (vz / s);
    o1.y = (double)w.w * (vw / s);
    *(double2*)(o + 0) = o0;
    *(double2*)(o + 2) = o1;
}

// ---------------------------------------------------------------------------
// f64 MFMA GEMM: C[m,n] = op( sum_k A[m,k] * W[n,k] )   A f64, W f32 (cast).
// 128x128 tile, BK=16, 4 waves each owning 64x64 via 4x4 tiles of
// v_mfma_f64_16x16x4. LDS [k][m]/[k][n], pad to 130 (fragment reads and
// staging writes both hit the 4-cycle b64 floor, no extra conflicts).
// A/B fragment maps: m=l%16, k=l/16 (universal); C/D map from runtime probe.
// Reg-prefetch of next k-tile hides global latency under MFMA.
// ---------------------------------------------------------------------------
#define MODE_SIG 0
#define MODE_PLAIN 1
#define MODE_ADD 2

#define BM 128
#define BN 128
#define BKK 16
#define LDT 130

__device__ __forceinline__ void gemm_mfma_f64(const double* __restrict__ A,
                                              const float* __restrict__ W,
                                              double* __restrict__ C,
                                              const double* __restrict__ Xadd,
                                              const int* __restrict__ maps,
                                              const int mode) {
    __shared__ double As[BKK][LDT];   // [k][m]
    __shared__ double Bs[BKK][LDT];   // [k][n]
    const int tid = threadIdx.x;
    const int m0 = blockIdx.y * BM;
    const int n0 = blockIdx.x * BN;

    const int lane = tid & 63;
    const int w = tid >> 6;
    const int wm = (w >> 1) * 64;
    const int wn = (w & 1) * 64;
    const int fr = lane & 15;         // fragment row/col (m or n = l%16)
    const int fk = lane >> 4;         // fragment k (l/16)

    // probed C/D maps for this lane
    const int4 rm4 = ((const int4*)maps)[lane];
    const int4 cm4 = ((const int4*)(maps + 256))[lane];
    const int rmap[4] = {rm4.x, rm4.y, rm4.z, rm4.w};
    const int cmap[4] = {cm4.x, cm4.y, cm4.z, cm4.w};

    dx4 acc[4][4];
    #pragma unroll
    for (int i = 0; i < 4; ++i)
        #pragma unroll
        for (int j = 0; j < 4; ++j) acc[i][j] = (dx4){0.0, 0.0, 0.0, 0.0};

    double2 pa[4];
    float4 pb[2];

    #define LOADG(k0)                                                          \
        {                                                                      \
            _Pragma("unroll")                                                  \
            for (int i = 0; i < 4; ++i) {                                      \
                const int c = tid + 256 * i;                                   \
                pa[i] = *(const double2*)(A + (size_t)(m0 + (c >> 3)) * DD +   \
                                          (k0) + (c & 7) * 2);                 \
            }                                                                  \
            _Pragma("unroll")                                                  \
            for (int i = 0; i < 2; ++i) {                                      \
                const int c = tid + 256 * i;                                   \
                pb[i] = *(const float4*)(W + (size_t)(n0 + (c >> 2)) * DD +    \
                                         (k0) + (c & 3) * 4);                  \
            }                                                                  \
        }

    LOADG(0);

    for (int k0 = 0; k0 < DD; k0 += BKK) {
        __syncthreads();
        #pragma unroll
        for (int i = 0; i < 4; ++i) {
            const int c = tid + 256 * i;
            const int m = c >> 3, j = c & 7;
            As[2 * j][m] = pa[i].x;
            As[2 * j + 1][m] = pa[i].y;
        }
        #pragma unroll
        for (int i = 0; i < 2; ++i) {
            const int c = tid + 256 * i;
            const int n = c >> 2, j = c & 3;
            Bs[4 * j + 0][n] = (double)pb[i].x;
            Bs[4 * j + 1][n] = (double)pb[i].y;
            Bs[4 * j + 2][n] = (double)pb[i].z;
            Bs[4 * j + 3][n] = (double)pb[i].w;
        }
        __syncthreads();
        if (k0 + BKK < DD) LOADG(k0 + BKK);

        #pragma unroll
        for (int ks = 0; ks < 4; ++ks) {
            double af[4], bf[4];
            #pragma unroll
            for (int t = 0; t < 4; ++t) af[t] = As[4 * ks + fk][wm + 16 * t + fr];
            #pragma unroll
            for (int t = 0; t < 4; ++t) bf[t] = Bs[4 * ks + fk][wn + 16 * t + fr];
            #pragma unroll
            for (int ti = 0; ti < 4; ++ti)
                #pragma unroll
                for (int tj = 0; tj < 4; ++tj)
                    acc[ti][tj] = __builtin_amdgcn_mfma_f64_16x16x4f64(
                        af[ti], bf[tj], acc[ti][tj], 0, 0, 0);
        }
    }
    #undef LOADG

    // epilogue via probed (row,col) maps
    #pragma unroll
    for (int ti = 0; ti < 4; ++ti) {
        #pragma unroll
        for (int tj = 0; tj < 4; ++tj) {
            #pragma unroll
            for (int r = 0; r < 4; ++r) {
                const int row = m0 + wm + 16 * ti + rmap[r];
                const int col = n0 + wn + 16 * tj + cmap[r];
                double v = acc[ti][tj][r];
                if (mode == MODE_SIG) v = 1.0 / (1.0 + exp(-v));
                if (mode == MODE_ADD) v += Xadd[(size_t)row * DD + col];
                C[(size_t)row * DD + col] = v;
            }
        }
    }
}

// R = sigmoid(Xn Wr^T), K = Xn Wk^T, V = Xn Wv^T   (z selects which)
__global__ __launch_bounds__(256, 2) void gemm_rkv(const float* __restrict__ Wr,
                                                   const float* __restrict__ Wk,
                                                   const float* __restrict__ Wv,
                                                   const int* __restrict__ maps) {
    const int z = blockIdx.z;
    const float* W = (z == 0) ? Wr : ((z == 1) ? Wk : Wv);
    double* C = g_ws + (size_t)(z + 1) * NN;
    gemm_mfma_f64(g_ws, W, C, nullptr, maps, z == 0 ? MODE_SIG : MODE_PLAIN);
}

// H = Xn + Y Wo^T   (Y = g_ws[2*NN), H overwrites V at g_ws[3*NN))
__global__ __launch_bounds__(256, 2) void gemm_wo(const float* __restrict__ Wo,
                                                  const int* __restrict__ maps) {
    gemm_mfma_f64(g_ws + 2 * NN, Wo, g_ws + 3 * NN, g_ws, maps, MODE_ADD);
}

// ---------------------------------------------------------------------------
// Kernel 3: per-channel recurrence over T (all f64). One thread per (b, d).
// ---------------------------------------------------------------------------
__global__ __launch_bounds__(256) void recur_k(const float* __restrict__ sp,
                                               const float* __restrict__ decay) {
    double* __restrict__ Kb = g_ws + 2 * NN;
    const double* __restrict__ V = g_ws + 3 * NN;
    const double* __restrict__ R = g_ws + NN;

    const int g = blockIdx.x * 256 + threadIdx.x;
    const int b = g >> 10;
    const int d = g & (DD - 1);

    const double dp = (double)decay[d];
    const double sg = 1.0 / (1.0 + exp(-dp));
    const double lam = sg * sg;

    const bool rope = (d < 32);
    double wt = 0.0;
    if (rope) {
        const int m = d >> 1;
        const double start = log(1.0 / 10000.0);
        const double step = (0.0 - start) / 15.0;
        const double val = (m == 15) ? 0.0 : (start + (double)m * step);
        wt = exp(val);
    }

    double num = 0.0, den = 0.0;
    const size_t base = (size_t)b * TT * DD + d;
    for (int t = 0; t < TT; ++t) {
        const size_t idx = base + (size_t)t * DD;
        const double k = Kb[idx];
        const double r = R[idx];
        double v = V[idx];
        if (rope) {
            const double vp = V[idx ^ 1ull];
            const double th = (double)sp[t] * wt;
            const double c_ = cos(th), s_ = sin(th);
            v = ((d & 1) == 0) ? (v * c_ - vp * s_) : (vp * s_ + v * c_);
        }
        const double w = exp(k);
        num = num * lam + w * v;
        den = den * lam + w;
        Kb[idx] = r * (num / (den + 1e-9));
    }
}

// ---------------------------------------------------------------------------
// Kernel 5: exact KWTA per row on f64 h; writes f32 out.
// ---------------------------------------------------------------------------
__global__ __launch_bounds__(256) void kwta_k(float* __restrict__ out) {
    const double* __restrict__ H = g_ws + 3 * NN;
    const size_t base = (size_t)blockIdx.x * DD;
    const int tid = threadIdx.x;
    double h[4];
    unsigned long long u[4];
    #pragma unroll
    for (int j = 0; j < 4; ++j) {
        h[j] = H[base + tid + 256 * j];
        u[j] = __double_as_longlong(fabs(h[j]));
    }

    __shared__ int scnt[64];
    if (tid < 64) scnt[tid] = 0;
    __syncthreads();

    unsigned long long thr = 0ull;
    #pragma unroll 1
    for (int bit = 62; bit >= 0; --bit) {
        const unsigned long long cand = thr | (1ull << bit);
        int c = (u[0] >= cand) + (u[1] >= cand) + (u[2] >= cand) + (u[3] >= cand);
        #pragma unroll
        for (int off = 32; off > 0; off >>= 1) c += __shfl_down(c, off, 64);
        if ((tid & 63) == 0) atomicAdd(&scnt[bit], c);
        __syncthreads();
        if (scnt[bit] >= KWTA_KEEP) thr = cand;
    }

    #pragma unroll
    for (int j = 0; j < 4; ++j)
        out[base + tid + 256 * j] = (u[j] >= thr) ? (float)h[j] : 0.0f;
}

// ---------------------------------------------------------------------------
extern "C" void kernel_launch(void* const* d_in, const int* in_sizes, int n_in,
                              void* d_out, int out_size, void* d_ws, size_t ws_size,
                              hipStream_t stream) {
    const float* x    = (const float*)d_in[0];
    const float* sp   = (const float*)d_in[1];
    const float* nw   = (const float*)d_in[2];
    const float* Wr   = (const float*)d_in[3];
    const float* Wk   = (const float*)d_in[4];
    const float* Wv   = (const float*)d_in[5];
    const float* Wo   = (const float*)d_in[6];
    const float* dec  = (const float*)d_in[7];
    float* out = (float*)d_out;
    int* maps = (int*)d_ws;   // 512 ints (2 KB): [0,256) row map, [256,512) col

    probe_k<<<1, 64, 0, stream>>>(maps);

    rmsnorm_k<<<NROWS, 256, 0, stream>>>(x, nw);

    dim3 g1(DD / BN, NROWS / BM, 3);
    gemm_rkv<<<g1, 256, 0, stream>>>(Wr, Wk, Wv, maps);

    recur_k<<<(BB * DD) / 256, 256, 0, stream>>>(sp, dec);

    dim3 g2(DD / BN, NROWS / BM, 1);
    gemm_wo<<<g2, 256, 0, stream>>>(Wo, maps);

    kwta_k<<<NROWS, 256, 0, stream>>>(out);
}